// Round 1
// baseline (98.868 us; speedup 1.0000x reference)
//
#include <hip/hip_runtime.h>
#include <math.h>

// Problem dims (fixed by reference)
#define BN  256   // batch
#define IN  512
#define HID 1024
#define OUT 512

#define KS1 4     // K-split layer 1 (512 i -> 4 chunks of 128)
#define KS2 8     // K-split layer 2 (1024 i -> 8 chunks of 128)
#define ICH 128   // i-chunk size (both layers)
#define G   8     // batch rows per thread

// hard-concrete deterministic gate: clip(sigmoid(q)*1.2 - 0.1, 0, 1)
__device__ __forceinline__ float gate(float q) {
    float s = 1.0f / (1.0f + expf(-q));
    float z = fmaf(s, 1.2f, -0.1f);
    return fminf(fmaxf(z, 0.0f), 1.0f);
}

// K1: m1[b,i] = 1 - x[b,i]*gate(qz1[i]); z2w[i] = gate(qz2[i])
__global__ __launch_bounds__(256) void k_prep(
        const float* __restrict__ x, const float* __restrict__ qz1,
        const float* __restrict__ qz2, float* __restrict__ m1,
        float* __restrict__ z2w) {
    int idx = blockIdx.x * 256 + threadIdx.x;
    if (idx < BN * IN) {
        m1[idx] = fmaf(-x[idx], gate(qz1[idx & (IN - 1)]), 1.0f);
    } else if (idx < BN * IN + HID) {
        int i = idx - BN * IN;
        z2w[i] = gate(qz2[i]);
    }
}

// K2: layer-1 partial products.
// grid (jt=4, bt=32, ks=4); block 256 threads; thread = 1 column j, G=8 batch rows.
// hp[ks][b][j] = prod_{i in chunk ks} (1 - m1[b,i]*W1[i,j])
__global__ __launch_bounds__(256) void k_layer1(
        const float* __restrict__ m1, const float* __restrict__ W1,
        float* __restrict__ hp) {
    __shared__ float mt[ICH][G];   // transposed m1 tile: [i][b], broadcast reads
    const int tid = threadIdx.x;
    const int j   = blockIdx.x * 256 + tid;
    const int b0  = blockIdx.y * G;
    const int i0  = blockIdx.z * ICH;

    for (int t = tid; t < ICH * G; t += 256) {
        int ii = t >> 3, b = t & 7;
        mt[ii][b] = m1[(b0 + b) * IN + i0 + ii];
    }
    __syncthreads();

    float acc[G];
#pragma unroll
    for (int k = 0; k < G; ++k) acc[k] = 1.0f;

    const float* wp = W1 + (size_t)i0 * HID + j;
#pragma unroll 4
    for (int ii = 0; ii < ICH; ++ii) {
        float w = wp[(size_t)ii * HID];
        float4 a = *reinterpret_cast<const float4*>(&mt[ii][0]);
        float4 c = *reinterpret_cast<const float4*>(&mt[ii][4]);
        acc[0] *= fmaf(-a.x, w, 1.0f);
        acc[1] *= fmaf(-a.y, w, 1.0f);
        acc[2] *= fmaf(-a.z, w, 1.0f);
        acc[3] *= fmaf(-a.w, w, 1.0f);
        acc[4] *= fmaf(-c.x, w, 1.0f);
        acc[5] *= fmaf(-c.y, w, 1.0f);
        acc[6] *= fmaf(-c.z, w, 1.0f);
        acc[7] *= fmaf(-c.w, w, 1.0f);
    }

    float* op = hp + (size_t)blockIdx.z * (BN * HID) + (size_t)b0 * HID + j;
#pragma unroll
    for (int k = 0; k < G; ++k) op[(size_t)k * HID] = acc[k];
}

// K3: layer-2 partial products. Staging fuses hp0*hp1*hp2*hp3 * z2.
// grid (jt=2, bt=32, ks=8); pp[ks][b][j] = prod_{i in chunk} (1 - xin2[b,i]*W2[i,j])
__global__ __launch_bounds__(256) void k_layer2(
        const float* __restrict__ hp, const float* __restrict__ z2w,
        const float* __restrict__ W2, float* __restrict__ pp) {
    __shared__ float xt[ICH][G];
    const int tid = threadIdx.x;
    const int j   = blockIdx.x * 256 + tid;
    const int b0  = blockIdx.y * G;
    const int i0  = blockIdx.z * ICH;

    for (int t = tid; t < ICH * G; t += 256) {
        int ii = t >> 3, b = t & 7;
        size_t gi = (size_t)(b0 + b) * HID + i0 + ii;
        float h = hp[gi] * hp[BN * HID + gi] * hp[2 * BN * HID + gi] *
                  hp[3 * BN * HID + gi];
        xt[ii][b] = h * z2w[i0 + ii];
    }
    __syncthreads();

    float acc[G];
#pragma unroll
    for (int k = 0; k < G; ++k) acc[k] = 1.0f;

    const float* wp = W2 + (size_t)i0 * OUT + j;
#pragma unroll 4
    for (int ii = 0; ii < ICH; ++ii) {
        float w = wp[(size_t)ii * OUT];
        float4 a = *reinterpret_cast<const float4*>(&xt[ii][0]);
        float4 c = *reinterpret_cast<const float4*>(&xt[ii][4]);
        acc[0] *= fmaf(-a.x, w, 1.0f);
        acc[1] *= fmaf(-a.y, w, 1.0f);
        acc[2] *= fmaf(-a.z, w, 1.0f);
        acc[3] *= fmaf(-a.w, w, 1.0f);
        acc[4] *= fmaf(-c.x, w, 1.0f);
        acc[5] *= fmaf(-c.y, w, 1.0f);
        acc[6] *= fmaf(-c.z, w, 1.0f);
        acc[7] *= fmaf(-c.w, w, 1.0f);
    }

    float* op = pp + (size_t)blockIdx.z * (BN * OUT) + (size_t)b0 * OUT + j;
#pragma unroll
    for (int k = 0; k < G; ++k) op[(size_t)k * OUT] = acc[k];
}

// K4: out[b,j] = 1 - prod_{ks} pp[ks][b][j]
__global__ __launch_bounds__(256) void k_final(
        const float* __restrict__ pp, float* __restrict__ out) {
    int idx = blockIdx.x * 256 + threadIdx.x;
    if (idx < BN * OUT) {
        float p = 1.0f;
#pragma unroll
        for (int k = 0; k < KS2; ++k) p *= pp[(size_t)k * (BN * OUT) + idx];
        out[idx] = 1.0f - p;
    }
}

extern "C" void kernel_launch(void* const* d_in, const int* in_sizes, int n_in,
                              void* d_out, int out_size, void* d_ws, size_t ws_size,
                              hipStream_t stream) {
    const float* x   = (const float*)d_in[0];
    const float* W1  = (const float*)d_in[1];
    const float* qz1 = (const float*)d_in[2];
    const float* W2  = (const float*)d_in[3];
    const float* qz2 = (const float*)d_in[4];
    float* out = (float*)d_out;
    float* ws  = (float*)d_ws;

    // ws layout (floats):
    float* m1  = ws;                          // 131072
    float* z2w = ws + 131072;                 // 1024
    float* hp  = ws + 132096;                 // KS1 * 256*1024 = 1048576
    float* pp  = ws + 132096 + 1048576;       // KS2 * 256*512  = 1048576
    // total ~8.9 MB

    k_prep  <<<(BN * IN + HID + 255) / 256, 256, 0, stream>>>(x, qz1, qz2, m1, z2w);
    k_layer1<<<dim3(HID / 256, BN / G, KS1), 256, 0, stream>>>(m1, W1, hp);
    k_layer2<<<dim3(OUT / 256, BN / G, KS2), 256, 0, stream>>>(hp, z2w, W2, pp);
    k_final <<<(BN * OUT + 255) / 256, 256, 0, stream>>>(pp, out);
}

// Round 3
// 95.306 us; speedup vs baseline: 1.0374x; 1.0374x over previous
//
#include <hip/hip_runtime.h>
#include <math.h>

// Problem dims (fixed by reference)
#define BN  256   // batch
#define IN  512
#define HID 1024
#define OUT 512

#define KS1 16            // K-split layer 1: 512 -> 16 chunks of 32
#define C1  (IN / KS1)    // 32
#define KS2 16            // K-split layer 2: 1024 -> 16 chunks of 64
#define C2  (HID / KS2)   // 64
#define G   8             // batch rows per thread (4 float2 pairs)

typedef float f32x2 __attribute__((ext_vector_type(2)));

// hard-concrete deterministic gate: clip(sigmoid(q)*1.2 - 0.1, 0, 1)
__device__ __forceinline__ float gate(float q) {
    float s = 1.0f / (1.0f + expf(-q));
    return fminf(fmaxf(fmaf(s, 1.2f, -0.1f), 0.0f), 1.0f);
}

// Layer 1 (fuzzy AND): hp[ks][b][j] = prod_{i in chunk ks} (1 - (1 - x*z1)*W1)
// thread: 4 j-columns (j0 = tid*4), 8 batch rows as 4 f32x2 pairs.
// grid (bt=32, ks=16), block 256.
__global__ __launch_bounds__(256) void k_layer1(
        const float* __restrict__ x, const float* __restrict__ qz1,
        const float* __restrict__ W1, float* __restrict__ hp) {
    __shared__ float sm[C1][G];    // negm[i][b] = x*z1 - 1  (= -(1-xin))
    const int tid = threadIdx.x;
    const int b0  = blockIdx.x * G;
    const int ks  = blockIdx.y;
    const int i0  = ks * C1;

    {   // stage: exactly one element per thread (C1*G == 256)
        int ii = tid >> 3, b = tid & 7;
        float z = gate(qz1[i0 + ii]);
        sm[ii][b] = fmaf(x[(size_t)(b0 + b) * IN + i0 + ii], z, -1.0f);
    }
    __syncthreads();

    const int j0 = tid * 4;
    const f32x2 one2 = {1.0f, 1.0f};
    f32x2 acc[4][4];
#pragma unroll
    for (int j = 0; j < 4; ++j)
#pragma unroll
        for (int p = 0; p < 4; ++p) acc[j][p] = one2;

    const float* wp = W1 + (size_t)i0 * HID + j0;
#pragma unroll 4
    for (int ii = 0; ii < C1; ++ii) {
        float4 w4  = *reinterpret_cast<const float4*>(wp + (size_t)ii * HID);
        float4 alo = *reinterpret_cast<const float4*>(&sm[ii][0]);
        float4 ahi = *reinterpret_cast<const float4*>(&sm[ii][4]);
        f32x2 ap[4];
        ap[0] = f32x2{alo.x, alo.y}; ap[1] = f32x2{alo.z, alo.w};
        ap[2] = f32x2{ahi.x, ahi.y}; ap[3] = f32x2{ahi.z, ahi.w};
        float wq[4] = {w4.x, w4.y, w4.z, w4.w};
#pragma unroll
        for (int j = 0; j < 4; ++j) {
            f32x2 wj = {wq[j], wq[j]};
#pragma unroll
            for (int p = 0; p < 4; ++p) {
                acc[j][p] *= ap[p] * wj + one2;   // v_pk_fma + v_pk_mul
            }
        }
    }

    float* op = hp + ((size_t)ks * BN + b0) * HID + j0;
#pragma unroll
    for (int b = 0; b < G; ++b) {
        const int p = b >> 1, h = b & 1;
        float4 v = {acc[0][p][h], acc[1][p][h], acc[2][p][h], acc[3][p][h]};
        *reinterpret_cast<float4*>(op + (size_t)b * HID) = v;
    }
}

// Layer 2 (fuzzy OR partials): pp[ks][b][j] = prod_{i in chunk} (1 - h*z2*W2)
// staging fuses the KS1-way hp combine and the z2 gate.
// thread: 2 j-columns (j0 = tid*2), 8 batch rows. grid (bt=32, ks=16).
__global__ __launch_bounds__(256) void k_layer2(
        const float* __restrict__ hp, const float* __restrict__ qz2,
        const float* __restrict__ W2, float* __restrict__ pp) {
    __shared__ float sm[C2][G];    // negx2[i][b] = -(h*z2)
    const int tid = threadIdx.x;
    const int b0  = blockIdx.x * G;
    const int ks  = blockIdx.y;
    const int i0  = ks * C2;

#pragma unroll
    for (int t = tid; t < C2 * G; t += 256) {   // 2 elements per thread
        int ii = t >> 3, b = t & 7;
        size_t gi = (size_t)(b0 + b) * HID + i0 + ii;
        float h = hp[gi];
#pragma unroll
        for (int k = 1; k < KS1; ++k) h *= hp[(size_t)k * (BN * HID) + gi];
        sm[ii][b] = -(h * gate(qz2[i0 + ii]));
    }
    __syncthreads();

    const int j0 = tid * 2;
    const f32x2 one2 = {1.0f, 1.0f};
    f32x2 acc[2][4];
#pragma unroll
    for (int j = 0; j < 2; ++j)
#pragma unroll
        for (int p = 0; p < 4; ++p) acc[j][p] = one2;

    const float* wp = W2 + (size_t)i0 * OUT + j0;
#pragma unroll 4
    for (int ii = 0; ii < C2; ++ii) {
        f32x2 w2   = *reinterpret_cast<const f32x2*>(wp + (size_t)ii * OUT);
        float4 alo = *reinterpret_cast<const float4*>(&sm[ii][0]);
        float4 ahi = *reinterpret_cast<const float4*>(&sm[ii][4]);
        f32x2 ap[4];
        ap[0] = f32x2{alo.x, alo.y}; ap[1] = f32x2{alo.z, alo.w};
        ap[2] = f32x2{ahi.x, ahi.y}; ap[3] = f32x2{ahi.z, ahi.w};
#pragma unroll
        for (int j = 0; j < 2; ++j) {
            f32x2 wj = {w2[j], w2[j]};
#pragma unroll
            for (int p = 0; p < 4; ++p) {
                acc[j][p] *= ap[p] * wj + one2;
            }
        }
    }

    float* op = pp + ((size_t)ks * BN + b0) * OUT + j0;
#pragma unroll
    for (int b = 0; b < G; ++b) {
        const int p = b >> 1, h = b & 1;
        f32x2 v = {acc[0][p][h], acc[1][p][h]};
        *reinterpret_cast<f32x2*>(op + (size_t)b * OUT) = v;
    }
}

// Final: out[b,j] = 1 - prod_{ks} pp[ks][b][j]   (grid exactly BN*OUT/256)
__global__ __launch_bounds__(256) void k_final(
        const float* __restrict__ pp, float* __restrict__ out) {
    int idx = blockIdx.x * 256 + threadIdx.x;
    float p = pp[idx];
#pragma unroll
    for (int k = 1; k < KS2; ++k) p *= pp[(size_t)k * (BN * OUT) + idx];
    out[idx] = 1.0f - p;
}

extern "C" void kernel_launch(void* const* d_in, const int* in_sizes, int n_in,
                              void* d_out, int out_size, void* d_ws, size_t ws_size,
                              hipStream_t stream) {
    const float* x   = (const float*)d_in[0];
    const float* W1  = (const float*)d_in[1];
    const float* qz1 = (const float*)d_in[2];
    const float* W2  = (const float*)d_in[3];
    const float* qz2 = (const float*)d_in[4];
    float* out = (float*)d_out;
    float* ws  = (float*)d_ws;

    // ws layout (floats): hp = KS1*BN*HID = 4M, pp = KS2*BN*OUT = 2M  (~25 MB)
    float* hp = ws;
    float* pp = ws + (size_t)KS1 * BN * HID;

    k_layer1<<<dim3(BN / G, KS1), 256, 0, stream>>>(x, qz1, W1, hp);
    k_layer2<<<dim3(BN / G, KS2), 256, 0, stream>>>(hp, qz2, W2, pp);
    k_final <<<(BN * OUT) / 256, 256, 0, stream>>>(pp, out);
}